// Round 1
// baseline (7294.806 us; speedup 1.0000x reference)
//
#include <hip/hip_runtime.h>
#include <math.h>

#define HW 4096
#define BB 32
#define EPSV 1e-5f

// ---------------- per-channel batchnorm stats (biased var) ----------------
__global__ __launch_bounds__(256) void bn_stats_kernel(
    const float* __restrict__ x, int C, float* __restrict__ mean, float* __restrict__ rstd) {
  int c = blockIdx.x;
  int tid = threadIdx.x;
  float s = 0.f, s2 = 0.f;
  for (int b = 0; b < BB; b++) {
    const float* p = x + ((size_t)b * C + c) * HW;
    for (int i = tid; i < HW; i += 256) { float t = p[i]; s += t; s2 += t * t; }
  }
  __shared__ float sh[2][256];
  sh[0][tid] = s; sh[1][tid] = s2;
  __syncthreads();
  for (int off = 128; off > 0; off >>= 1) {
    if (tid < off) { sh[0][tid] += sh[0][tid + off]; sh[1][tid] += sh[1][tid + off]; }
    __syncthreads();
  }
  if (tid == 0) {
    float N = (float)(BB * HW);
    float m = sh[0][0] / N;
    float var = sh[1][0] / N - m * m;
    mean[c] = m;
    rstd[c] = rsqrtf(var + EPSV);
  }
}

// ---------------- fold batchnorm+shortcut into per-channel affine ----------------
__global__ void coeffs_kernel(const float* __restrict__ mean, const float* __restrict__ rstd,
                              int ch0, const float* __restrict__ a_pre, int branch,
                              float* __restrict__ alpha, float* __restrict__ beta) {
  int c = threadIdx.x;  // 32 threads
  float ap = a_pre[branch];
  float r = rstd[ch0 + c], m = mean[ch0 + c];
  alpha[c] = 0.5f * r + 0.01f * ap;
  beta[c]  = -0.5f * m * r;
}

// ---------------- 3x3 pad-1 conv, 32 input channels, fused input affine ----------------
// Handles static convs (wstride_b=0, alpha/beta set) and the per-sample dynamic conv
// (wstride_b=64*288, alpha=nullptr -> identity affine).
__global__ __launch_bounds__(256) void conv3x3_kernel(
    const float* __restrict__ xin, int ch0, int cstride,
    const float* __restrict__ w, size_t wstride_b,
    const float* __restrict__ alpha, const float* __restrict__ beta,
    float* __restrict__ out, int Cout) {
  int b = blockIdx.z;
  int o0 = blockIdx.y * 4;
  int p = blockIdx.x * 256 + threadIdx.x;
  __shared__ float ws_[4 * 288];
  __shared__ float al[32], be[32];
  const float* wb = w + (size_t)b * wstride_b + (size_t)o0 * 288;
  for (int i = threadIdx.x; i < 4 * 288; i += 256) ws_[i] = wb[i];
  if (threadIdx.x < 32) {
    al[threadIdx.x] = alpha ? alpha[threadIdx.x] : 1.0f;
    be[threadIdx.x] = alpha ? beta[threadIdx.x] : 0.0f;
  }
  __syncthreads();
  int y = p >> 6, xx = p & 63;
  float acc0 = 0.f, acc1 = 0.f, acc2 = 0.f, acc3 = 0.f;
  const float* xb = xin + ((size_t)b * cstride + ch0) * HW;
  for (int c = 0; c < 32; c++) {
    const float* xc = xb + c * HW;
    float a = al[c], bb = be[c];
    const float* wc = ws_ + c * 9;
    #pragma unroll
    for (int dy = 0; dy < 3; dy++) {
      int yy = y + dy - 1;
      if ((unsigned)yy >= 64u) continue;
      #pragma unroll
      for (int dx = 0; dx < 3; dx++) {
        int xv = xx + dx - 1;
        if ((unsigned)xv >= 64u) continue;
        float h = a * xc[(yy << 6) + xv] + bb;
        int wi = dy * 3 + dx;
        acc0 += wc[wi] * h;
        acc1 += wc[288 + wi] * h;
        acc2 += wc[576 + wi] * h;
        acc3 += wc[864 + wi] * h;
      }
    }
  }
  size_t ob = ((size_t)b * Cout + o0) * HW + p;
  out[ob] = acc0;
  out[ob + HW] = acc1;
  out[ob + 2 * HW] = acc2;
  out[ob + 3 * HW] = acc3;
}

// ---------------- attn k=3: a1[b,o,i,kk] = sum_{441 pts} y1[b,i,pt]*y2[b,o,pt] / sqrt(288)
__global__ __launch_bounds__(256) void attn1_kernel(
    const float* __restrict__ y1, const float* __restrict__ y2, float* __restrict__ a1) {
  int kk = blockIdx.x;   // 0..8
  int b = blockIdx.y;
  int di = kk / 3, dj = kk % 3;
  int tid = threadIdx.x;
  int o = tid >> 2;          // 0..63
  int i0 = (tid & 3) * 8;    // 0,8,16,24
  __shared__ float s1[8][32];
  __shared__ float s2[8][64];
  float acc[8] = {0, 0, 0, 0, 0, 0, 0, 0};
  const float* y1b = y1 + (size_t)b * 32 * HW;
  const float* y2b = y2 + (size_t)b * 64 * HW;
  for (int l0 = 0; l0 < 441; l0 += 8) {
    for (int t = tid; t < 768; t += 256) {
      int lj = t / 96, wh = t % 96;
      int l = l0 + lj;
      float v = 0.f;
      if (l < 441) {
        int pp = l / 21, qq = l % 21;
        int off = (3 * pp + di) * 64 + (3 * qq + dj);
        v = (wh < 32) ? y1b[(size_t)wh * HW + off] : y2b[(size_t)(wh - 32) * HW + off];
      }
      if (wh < 32) s1[lj][wh] = v; else s2[lj][wh - 32] = v;
    }
    __syncthreads();
    #pragma unroll
    for (int lj = 0; lj < 8; lj++) {
      float yo = s2[lj][o];
      #pragma unroll
      for (int ii = 0; ii < 8; ii++) acc[ii] += s1[lj][i0 + ii] * yo;
    }
    __syncthreads();
  }
  const float scale = 0.05892556509887896f;  // 1/sqrt(288)
  for (int ii = 0; ii < 8; ii++)
    a1[(((size_t)b * 64 + o) * 32 + i0 + ii) * 9 + kk] = acc[ii] * scale;
}

// ---------------- attn k=1 + softmax over i ----------------
__global__ __launch_bounds__(256) void attn2_kernel(
    const float* __restrict__ y1, const float* __restrict__ y2, float* __restrict__ a2) {
  int o = blockIdx.x, b = blockIdx.y;
  int tid = threadIdx.x;
  int i = tid & 31, pg = tid >> 5;  // 8 pixel groups
  const float* y1b = y1 + ((size_t)b * 32 + i) * HW;
  const float* y2b = y2 + ((size_t)b * 64 + o) * HW;
  float acc = 0.f;
  for (int p = pg; p < HW; p += 8) acc += y1b[p] * y2b[p];
  __shared__ float sh[8][32];
  __shared__ float sm[33];
  sh[pg][i] = acc;
  __syncthreads();
  if (tid < 32) {
    float s = 0.f;
    for (int g = 0; g < 8; g++) s += sh[g][tid];
    sm[tid] = s * 0.17677669529663687f;  // 1/sqrt(32)
  }
  __syncthreads();
  if (tid == 0) {
    float mx = -1e30f;
    for (int k = 0; k < 32; k++) mx = fmaxf(mx, sm[k]);
    float sum = 0.f;
    for (int k = 0; k < 32; k++) { float e = expf(sm[k] - mx); sm[k] = e; sum += e; }
    sm[32] = 1.0f / sum;
  }
  __syncthreads();
  if (tid < 32) a2[((size_t)b * 64 + o) * 32 + tid] = sm[tid] * sm[32];
}

// ---------------- ak = a2 * (a1 + aw) ----------------
__global__ __launch_bounds__(256) void ak_kernel(
    const float* __restrict__ a1, const float* __restrict__ a2,
    const float* __restrict__ aw, float* __restrict__ akb) {
  int idx = blockIdx.x * 256 + threadIdx.x;  // B*64*32*9 = 589824
  int kk9 = idx % 288;  // i*9+kk
  int bo = idx / 288;   // b*64+o
  int o = bo & 63;
  int i = kk9 / 9;
  akb[idx] = a2[(size_t)bo * 32 + i] * (a1[idx] + aw[(size_t)o * 288 + kk9]);
}

// ---------------- output batchnorm affine + branch combine ----------------
__global__ __launch_bounds__(256) void finalize_kernel(
    const float* __restrict__ v, const float* __restrict__ vmean, const float* __restrict__ vrstd,
    const float* __restrict__ a_post, int branch, int mode,
    float* __restrict__ acc, float* __restrict__ ysave,
    const float* __restrict__ x, const float* __restrict__ cm, float* __restrict__ out) {
  size_t idx = (size_t)blockIdx.x * 256 + threadIdx.x;  // B*64*HW
  int o = (int)((idx >> 12) & 63);
  float ap = a_post[branch];
  float ga = 0.5f * vrstd[o] + 0.6f * ap;
  float gb = -0.5f * vmean[o] * vrstd[o];
  float yv = ga * v[idx] + gb;
  if (mode == 0) acc[idx] = yv;
  else if (mode == 1) acc[idx] += yv;
  else if (mode == 2) ysave[idx] = yv;
  else out[idx] = 0.99f * cm[0] * x[idx] + (acc[idx] + ysave[idx] * yv) * 0.5773502691896258f;
}

extern "C" void kernel_launch(void* const* d_in, const int* in_sizes, int n_in,
                              void* d_out, int out_size, void* d_ws, size_t ws_size,
                              hipStream_t stream) {
  const float* x      = (const float*)d_in[0];
  const float* wk1c1  = (const float*)d_in[1];
  const float* wk1c2  = (const float*)d_in[2];
  const float* wk2c1  = (const float*)d_in[3];
  const float* wk2c2  = (const float*)d_in[4];
  const float* wconv  = (const float*)d_in[5];
  const float* attn_w = (const float*)d_in[6];
  const float* a_pre  = (const float*)d_in[7];
  const float* a_post = (const float*)d_in[8];
  const float* cm     = (const float*)d_in[9];
  float* out = (float*)d_out;

  float* ws = (float*)d_ws;
  float* bufA  = ws;                   // 4,194,304  (c1a / c2a / cc)
  float* bufB  = bufA + 4194304;       // 8,388,608  (c1b / c2b)
  float* vbuf  = bufB + 8388608;       // 8,388,608
  float* accb  = vbuf + 8388608;       // 8,388,608
  float* ysave = accb + 8388608;       // 8,388,608
  float* a1    = ysave + 8388608;      // 589,824
  float* a2    = a1 + 589824;          // 65,536
  float* akb   = a2 + 65536;           // 589,824
  float* xmean = akb + 589824;         // 64
  float* xrstd = xmean + 64;           // 64
  float* vmean = xrstd + 64;           // 64
  float* vrstd = vmean + 64;           // 64
  float* alphab = vrstd + 64;          // 32
  float* betab  = alphab + 32;         // 32

  // per-channel stats of x (covers both halves)
  bn_stats_kernel<<<64, 256, 0, stream>>>(x, 64, xmean, xrstd);

  for (int br = 0; br < 4; br++) {
    int ch0 = (br & 1) * 32;
    coeffs_kernel<<<1, 32, 0, stream>>>(xmean, xrstd, ch0, a_pre, br, alphab, betab);

    // k=3 attention pair
    conv3x3_kernel<<<dim3(16, 8, 32), 256, 0, stream>>>(
        x, ch0, 64, wk1c1 + (size_t)br * 32 * 288, 0, alphab, betab, bufA, 32);
    conv3x3_kernel<<<dim3(16, 16, 32), 256, 0, stream>>>(
        x, ch0, 64, wk1c2 + (size_t)br * 64 * 288, 0, alphab, betab, bufB, 64);
    attn1_kernel<<<dim3(9, 32), 256, 0, stream>>>(bufA, bufB, a1);

    // k=1 attention pair + softmax
    conv3x3_kernel<<<dim3(16, 8, 32), 256, 0, stream>>>(
        x, ch0, 64, wk2c1 + (size_t)br * 32 * 288, 0, alphab, betab, bufA, 32);
    conv3x3_kernel<<<dim3(16, 16, 32), 256, 0, stream>>>(
        x, ch0, 64, wk2c2 + (size_t)br * 64 * 288, 0, alphab, betab, bufB, 64);
    attn2_kernel<<<dim3(64, 32), 256, 0, stream>>>(bufA, bufB, a2);

    // combined attention kernel
    ak_kernel<<<2304, 256, 0, stream>>>(a1, a2, attn_w + (size_t)br * 64 * 288, akb);

    // cc = conv(h, wconv), then per-sample dynamic conv v = ak (*) cc
    conv3x3_kernel<<<dim3(16, 8, 32), 256, 0, stream>>>(
        x, ch0, 64, wconv + (size_t)br * 32 * 288, 0, alphab, betab, bufA, 32);
    conv3x3_kernel<<<dim3(16, 16, 32), 256, 0, stream>>>(
        bufA, 0, 32, akb, (size_t)64 * 288, nullptr, nullptr, vbuf, 64);

    bn_stats_kernel<<<64, 256, 0, stream>>>(vbuf, 64, vmean, vrstd);
    finalize_kernel<<<32768, 256, 0, stream>>>(
        vbuf, vmean, vrstd, a_post, br, br, accb, ysave, x, cm, out);
  }
}

// Round 2
// 5439.811 us; speedup vs baseline: 1.3410x; 1.3410x over previous
//
#include <hip/hip_runtime.h>
#include <math.h>

#define HW 4096
#define BB 32
#define EPSV 1e-5f

// ---------------- per-channel batchnorm stats (biased var) ----------------
__global__ __launch_bounds__(256) void bn_stats_kernel(
    const float* __restrict__ x, int C, float* __restrict__ mean, float* __restrict__ rstd) {
  int c = blockIdx.x;
  int tid = threadIdx.x;
  float s = 0.f, s2 = 0.f;
  for (int b = 0; b < BB; b++) {
    const float* p = x + ((size_t)b * C + c) * HW;
    for (int i = tid; i < HW; i += 256) { float t = p[i]; s += t; s2 += t * t; }
  }
  __shared__ float sh[2][256];
  sh[0][tid] = s; sh[1][tid] = s2;
  __syncthreads();
  for (int off = 128; off > 0; off >>= 1) {
    if (tid < off) { sh[0][tid] += sh[0][tid + off]; sh[1][tid] += sh[1][tid + off]; }
    __syncthreads();
  }
  if (tid == 0) {
    float N = (float)(BB * HW);
    float m = sh[0][0] / N;
    float var = sh[1][0] / N - m * m;
    mean[c] = m;
    rstd[c] = rsqrtf(var + EPSV);
  }
}

// ---------------- fold batchnorm+shortcut into per-channel affine ----------------
__global__ void coeffs_kernel(const float* __restrict__ mean, const float* __restrict__ rstd,
                              int ch0, const float* __restrict__ a_pre, int branch,
                              float* __restrict__ alpha, float* __restrict__ beta) {
  int c = threadIdx.x;  // 32 threads
  float ap = a_pre[branch];
  float r = rstd[ch0 + c], m = mean[ch0 + c];
  alpha[c] = 0.5f * r + 0.01f * ap;
  beta[c]  = -0.5f * m * r;
}

// ---------------- 3x3 pad-1 conv, 32 input channels, fused input affine ----------------
__global__ __launch_bounds__(256) void conv3x3_kernel(
    const float* __restrict__ xin, int ch0, int cstride,
    const float* __restrict__ w, size_t wstride_b,
    const float* __restrict__ alpha, const float* __restrict__ beta,
    float* __restrict__ out, int Cout) {
  int b = blockIdx.z;
  int o0 = blockIdx.y * 4;
  int p = blockIdx.x * 256 + threadIdx.x;
  __shared__ float ws_[4 * 288];
  __shared__ float al[32], be[32];
  const float* wb = w + (size_t)b * wstride_b + (size_t)o0 * 288;
  for (int i = threadIdx.x; i < 4 * 288; i += 256) ws_[i] = wb[i];
  if (threadIdx.x < 32) {
    al[threadIdx.x] = alpha ? alpha[threadIdx.x] : 1.0f;
    be[threadIdx.x] = alpha ? beta[threadIdx.x] : 0.0f;
  }
  __syncthreads();
  int y = p >> 6, xx = p & 63;
  float acc0 = 0.f, acc1 = 0.f, acc2 = 0.f, acc3 = 0.f;
  const float* xb = xin + ((size_t)b * cstride + ch0) * HW;
  for (int c = 0; c < 32; c++) {
    const float* xc = xb + c * HW;
    float a = al[c], bb = be[c];
    const float* wc = ws_ + c * 9;
    #pragma unroll
    for (int dy = 0; dy < 3; dy++) {
      int yy = y + dy - 1;
      if ((unsigned)yy >= 64u) continue;
      #pragma unroll
      for (int dx = 0; dx < 3; dx++) {
        int xv = xx + dx - 1;
        if ((unsigned)xv >= 64u) continue;
        float h = a * xc[(yy << 6) + xv] + bb;
        int wi = dy * 3 + dx;
        acc0 += wc[wi] * h;
        acc1 += wc[288 + wi] * h;
        acc2 += wc[576 + wi] * h;
        acc3 += wc[864 + wi] * h;
      }
    }
  }
  size_t ob = ((size_t)b * Cout + o0) * HW + p;
  out[ob] = acc0;
  out[ob + HW] = acc1;
  out[ob + 2 * HW] = acc2;
  out[ob + 3 * HW] = acc3;
}

// ---------------- attn k=3 partials: coalesced row staging, kk = (r%3)*3 + c%3 ----------------
// grid (21, 32): blockIdx.x = rc*7+rg; block handles rows r = rc+9*rg+3*j, j=0..2 (all < 63)
// part1[rg][b][o][i][9] partial sums (cols 0..62 bucketed by c%3)
__global__ __launch_bounds__(256) void attn1_partial_kernel(
    const float* __restrict__ y1, const float* __restrict__ y2, float* __restrict__ part) {
  int rc = blockIdx.x / 7, rg = blockIdx.x % 7;
  int b = blockIdx.y;
  __shared__ float s1[32][65];
  __shared__ float s2[64][65];
  int tid = threadIdx.x;
  int o = tid >> 2, i0 = (tid & 3) * 8;
  int col = tid & 63, rw = tid >> 6;
  float acc[8][3] = {};
  const float* y1b = y1 + (size_t)b * 32 * HW;
  const float* y2b = y2 + (size_t)b * 64 * HW;
  for (int j = 0; j < 3; j++) {
    int r = rc + 9 * rg + 3 * j;
    __syncthreads();
    for (int c = rw; c < 32; c += 4) s1[c][col] = y1b[(size_t)c * HW + (r << 6) + col];
    for (int c = rw; c < 64; c += 4) s2[c][col] = y2b[(size_t)c * HW + (r << 6) + col];
    __syncthreads();
    for (int c3 = 0; c3 < 21; c3++) {
      #pragma unroll
      for (int cc = 0; cc < 3; cc++) {
        int c = 3 * c3 + cc;
        float yo = s2[o][c];
        #pragma unroll
        for (int ii = 0; ii < 8; ii++) acc[ii][cc] += s1[i0 + ii][c] * yo;
      }
    }
  }
  size_t base = ((size_t)rg * 32 + b) * 2048 + o * 32 + i0;
  for (int ii = 0; ii < 8; ii++)
    #pragma unroll
    for (int cc = 0; cc < 3; cc++)
      part[(base + ii) * 9 + rc * 3 + cc] = acc[ii][cc];
}

// ---------------- attn k=1 partials: coalesced pixel-tiled split-K ----------------
// grid (8, 32): block handles 512 pixels; part2[ps][b][o*32+i]
__global__ __launch_bounds__(256) void attn2_partial_kernel(
    const float* __restrict__ y1, const float* __restrict__ y2, float* __restrict__ part) {
  int ps = blockIdx.x, b = blockIdx.y;
  __shared__ float s1[32][65];
  __shared__ float s2[64][65];
  int tid = threadIdx.x;
  int o = tid >> 2, i0 = (tid & 3) * 8;
  int col = tid & 63, rw = tid >> 6;
  float acc[8] = {};
  const float* y1b = y1 + (size_t)b * 32 * HW + ps * 512;
  const float* y2b = y2 + (size_t)b * 64 * HW + ps * 512;
  for (int t = 0; t < 8; t++) {
    __syncthreads();
    for (int c = rw; c < 32; c += 4) s1[c][col] = y1b[(size_t)c * HW + t * 64 + col];
    for (int c = rw; c < 64; c += 4) s2[c][col] = y2b[(size_t)c * HW + t * 64 + col];
    __syncthreads();
    #pragma unroll 8
    for (int p = 0; p < 64; p++) {
      float yo = s2[o][p];
      #pragma unroll
      for (int ii = 0; ii < 8; ii++) acc[ii] += s1[i0 + ii][p] * yo;
    }
  }
  size_t base = ((size_t)ps * 32 + b) * 2048 + o * 32 + i0;
  for (int ii = 0; ii < 8; ii++) part[base + ii] = acc[ii];
}

// ---------------- fused: reduce partials + softmax(a2) + ak = a2*(a1+aw) ----------------
// grid (64, 32) = (o, b), 320 threads
__global__ __launch_bounds__(320) void fused_ak_kernel(
    const float* __restrict__ part1, const float* __restrict__ part2,
    const float* __restrict__ aw, float* __restrict__ akb) {
  int o = blockIdx.x, b = blockIdx.y;
  int tid = threadIdx.x;
  __shared__ float sm[33];
  if (tid < 32) {
    float s = 0.f;
    for (int ps = 0; ps < 8; ps++) s += part2[((size_t)ps * 32 + b) * 2048 + o * 32 + tid];
    sm[tid] = s * 0.17677669529663687f;  // 1/sqrt(32)
  }
  __syncthreads();
  if (tid == 0) {
    float mx = -1e30f;
    for (int k = 0; k < 32; k++) mx = fmaxf(mx, sm[k]);
    float sum = 0.f;
    for (int k = 0; k < 32; k++) { float e = expf(sm[k] - mx); sm[k] = e; sum += e; }
    sm[32] = 1.0f / sum;
  }
  __syncthreads();
  if (tid < 288) {
    int i = tid / 9, kk = tid % 9;
    size_t idx9 = (size_t)(o * 32 + i) * 9 + kk;
    float a1v = 0.f;
    for (int rg = 0; rg < 7; rg++)
      a1v += part1[((size_t)rg * 32 + b) * 2048 * 9 + idx9];
    a1v *= 0.05892556509887896f;  // 1/sqrt(288)
    float a2v = sm[i] * sm[32];
    akb[(((size_t)b * 64 + o) * 32 + i) * 9 + kk] = a2v * (a1v + aw[idx9]);
  }
}

// ---------------- output batchnorm affine + branch combine ----------------
__global__ __launch_bounds__(256) void finalize_kernel(
    const float* __restrict__ v, const float* __restrict__ vmean, const float* __restrict__ vrstd,
    const float* __restrict__ a_post, int branch, int mode,
    float* __restrict__ acc, float* __restrict__ ysave,
    const float* __restrict__ x, const float* __restrict__ cm, float* __restrict__ out) {
  size_t idx = (size_t)blockIdx.x * 256 + threadIdx.x;  // B*64*HW
  int o = (int)((idx >> 12) & 63);
  float ap = a_post[branch];
  float ga = 0.5f * vrstd[o] + 0.6f * ap;
  float gb = -0.5f * vmean[o] * vrstd[o];
  float yv = ga * v[idx] + gb;
  if (mode == 0) acc[idx] = yv;
  else if (mode == 1) acc[idx] += yv;
  else if (mode == 2) ysave[idx] = yv;
  else out[idx] = 0.99f * cm[0] * x[idx] + (acc[idx] + ysave[idx] * yv) * 0.5773502691896258f;
}

extern "C" void kernel_launch(void* const* d_in, const int* in_sizes, int n_in,
                              void* d_out, int out_size, void* d_ws, size_t ws_size,
                              hipStream_t stream) {
  const float* x      = (const float*)d_in[0];
  const float* wk1c1  = (const float*)d_in[1];
  const float* wk1c2  = (const float*)d_in[2];
  const float* wk2c1  = (const float*)d_in[3];
  const float* wk2c2  = (const float*)d_in[4];
  const float* wconv  = (const float*)d_in[5];
  const float* attn_w = (const float*)d_in[6];
  const float* a_pre  = (const float*)d_in[7];
  const float* a_post = (const float*)d_in[8];
  const float* cm     = (const float*)d_in[9];
  float* out = (float*)d_out;

  float* ws = (float*)d_ws;
  float* bufA  = ws;                   // 4,194,304  (c1a / c2a / cc)
  float* bufB  = bufA + 4194304;       // 8,388,608  (c1b / c2b)
  float* vbuf  = bufB + 8388608;       // 8,388,608 ; part1 aliases (needs 4,128,768)
  float* accb  = vbuf + 8388608;       // 8,388,608
  float* ysave = accb + 8388608;       // 8,388,608
  float* part2 = ysave + 8388608;      // 589,824 slot (needs 524,288)
  float* a2u   = part2 + 589824;       // 65,536 (unused, kept for layout stability)
  float* akb   = a2u + 65536;          // 589,824
  float* xmean = akb + 589824;         // 64
  float* xrstd = xmean + 64;           // 64
  float* vmean = xrstd + 64;           // 64
  float* vrstd = vmean + 64;           // 64
  float* alphab = vrstd + 64;          // 32
  float* betab  = alphab + 32;         // 32
  float* part1 = vbuf;                 // alias

  bn_stats_kernel<<<64, 256, 0, stream>>>(x, 64, xmean, xrstd);

  for (int br = 0; br < 4; br++) {
    int ch0 = (br & 1) * 32;
    coeffs_kernel<<<1, 32, 0, stream>>>(xmean, xrstd, ch0, a_pre, br, alphab, betab);

    // k=3 attention pair
    conv3x3_kernel<<<dim3(16, 8, 32), 256, 0, stream>>>(
        x, ch0, 64, wk1c1 + (size_t)br * 32 * 288, 0, alphab, betab, bufA, 32);
    conv3x3_kernel<<<dim3(16, 16, 32), 256, 0, stream>>>(
        x, ch0, 64, wk1c2 + (size_t)br * 64 * 288, 0, alphab, betab, bufB, 64);
    attn1_partial_kernel<<<dim3(21, 32), 256, 0, stream>>>(bufA, bufB, part1);

    // k=1 attention pair
    conv3x3_kernel<<<dim3(16, 8, 32), 256, 0, stream>>>(
        x, ch0, 64, wk2c1 + (size_t)br * 32 * 288, 0, alphab, betab, bufA, 32);
    conv3x3_kernel<<<dim3(16, 16, 32), 256, 0, stream>>>(
        x, ch0, 64, wk2c2 + (size_t)br * 64 * 288, 0, alphab, betab, bufB, 64);
    attn2_partial_kernel<<<dim3(8, 32), 256, 0, stream>>>(bufA, bufB, part2);

    // reduce + softmax + combine
    fused_ak_kernel<<<dim3(64, 32), 320, 0, stream>>>(
        part1, part2, attn_w + (size_t)br * 64 * 288, akb);

    // cc = conv(h, wconv), then per-sample dynamic conv v = ak (*) cc
    conv3x3_kernel<<<dim3(16, 8, 32), 256, 0, stream>>>(
        x, ch0, 64, wconv + (size_t)br * 32 * 288, 0, alphab, betab, bufA, 32);
    conv3x3_kernel<<<dim3(16, 16, 32), 256, 0, stream>>>(
        bufA, 0, 32, akb, (size_t)64 * 288, nullptr, nullptr, vbuf, 64);

    bn_stats_kernel<<<64, 256, 0, stream>>>(vbuf, 64, vmean, vrstd);
    finalize_kernel<<<32768, 256, 0, stream>>>(
        vbuf, vmean, vrstd, a_post, br, br, accb, ysave, x, cm, out);
  }
}

// Round 4
// 914.817 us; speedup vs baseline: 7.9741x; 5.9463x over previous
//
#include <hip/hip_runtime.h>
#include <math.h>

#define HW 4096
#define BB 32
#define EPSV 1e-5f

typedef _Float16 half8 __attribute__((ext_vector_type(8)));
typedef float f32x4 __attribute__((ext_vector_type(4)));
union H8 { half8 v; ushort4 q[2]; uint4 u4; };

__device__ __forceinline__ float tofloat(const float& v) { return v; }
__device__ __forceinline__ float tofloat(const _Float16& v) { return (float)v; }

// ---------------- bn stats: partial + reduce ----------------
template <typename T>
__global__ __launch_bounds__(256) void bn_partial_kernel(
    const T* __restrict__ x, int C, float* __restrict__ pstat) {
  int c = blockIdx.x, s = blockIdx.y;
  int tid = threadIdx.x;
  float sm = 0.f, s2 = 0.f;
  for (int b = s * 4; b < s * 4 + 4; b++) {
    const T* p = x + ((size_t)b * C + c) * HW;
    for (int i = tid; i < HW; i += 256) { float t = tofloat(p[i]); sm += t; s2 += t * t; }
  }
  __shared__ float sh[2][256];
  sh[0][tid] = sm; sh[1][tid] = s2;
  __syncthreads();
  for (int off = 128; off > 0; off >>= 1) {
    if (tid < off) { sh[0][tid] += sh[0][tid + off]; sh[1][tid] += sh[1][tid + off]; }
    __syncthreads();
  }
  if (tid == 0) {
    pstat[((size_t)s * 64 + c) * 2] = sh[0][0];
    pstat[((size_t)s * 64 + c) * 2 + 1] = sh[1][0];
  }
}

__global__ void bn_reduce_kernel(const float* __restrict__ pstat, float N,
                                 float* __restrict__ mean, float* __restrict__ rstd) {
  int c = threadIdx.x;  // 64
  float s = 0.f, s2 = 0.f;
  for (int k = 0; k < 8; k++) {
    s += pstat[((size_t)k * 64 + c) * 2];
    s2 += pstat[((size_t)k * 64 + c) * 2 + 1];
  }
  float m = s / N;
  mean[c] = m;
  rstd[c] = rsqrtf(s2 / N - m * m + EPSV);
}

// ---------------- fold batchnorm+shortcut into per-channel affine ----------------
__global__ void coeffs_kernel(const float* __restrict__ mean, const float* __restrict__ rstd,
                              int ch0, const float* __restrict__ a_pre, int branch,
                              float* __restrict__ alpha, float* __restrict__ beta) {
  int c = threadIdx.x;  // 32
  float ap = a_pre[branch];
  float r = rstd[ch0 + c], m = mean[ch0 + c];
  alpha[c] = 0.5f * r + 0.01f * ap;
  beta[c]  = -0.5f * m * r;
}

// ---------------- pack static conv weights into MFMA A-fragment order ----------------
// wpk[br][chunk14][tap9][lane64][j8]; A row o = chunk*16+(lane&15); k(c) = j<4 ? 4g+j : 16+4g+j-4
__global__ __launch_bounds__(256) void pack_static_kernel(
    const float* __restrict__ wk1c1, const float* __restrict__ wk1c2,
    const float* __restrict__ wk2c1, const float* __restrict__ wk2c2,
    const float* __restrict__ wconv, _Float16* __restrict__ wpk) {
  int idx = blockIdx.x * 256 + threadIdx.x;  // 258048
  int j = idx & 7, lane = (idx >> 3) & 63;
  int tap = (idx >> 9) % 9;
  int chunk = (idx / 4608) % 14;
  int br = idx / 64512;
  int g = lane >> 4;
  int c = (j < 4) ? 4 * g + j : 16 + 4 * g + (j - 4);
  const float* src; int ol0;
  if (chunk < 2)       { src = wk1c1 + (size_t)br * 32 * 288; ol0 = chunk * 16; }
  else if (chunk < 6)  { src = wk1c2 + (size_t)br * 64 * 288; ol0 = (chunk - 2) * 16; }
  else if (chunk < 8)  { src = wk2c1 + (size_t)br * 32 * 288; ol0 = (chunk - 6) * 16; }
  else if (chunk < 12) { src = wk2c2 + (size_t)br * 64 * 288; ol0 = (chunk - 8) * 16; }
  else                 { src = wconv + (size_t)br * 32 * 288; ol0 = (chunk - 12) * 16; }
  int o = ol0 + (lane & 15);
  wpk[idx] = (_Float16)(src[((size_t)o * 32 + c) * 9 + tap]);
}

// ---------------- pack dynamic (per-sample) weights ----------------
__global__ __launch_bounds__(256) void pack_dyn_kernel(
    const float* __restrict__ akb, _Float16* __restrict__ wdyn) {
  int idx = blockIdx.x * 256 + threadIdx.x;  // 589824
  int j = idx & 7, lane = (idx >> 3) & 63;
  int tap = (idx >> 9) % 9;
  int chunk = (idx / 4608) & 3;
  int b = idx / 18432;
  int g = lane >> 4;
  int c = (j < 4) ? 4 * g + j : 16 + 4 * g + (j - 4);
  int o = chunk * 16 + (lane & 15);
  wdyn[idx] = (_Float16)(akb[(((size_t)b * 64 + o) * 32 + c) * 9 + tap]);
}

// ---------------- MFMA conv: 9 shifted K=32 GEMMs; MODE0 = 5 static convs, MODE1 = dynamic ----------------
template <int MODE>
__global__ __launch_bounds__(256) void conv_mfma_kernel(
    const float* __restrict__ xin, int ch0,
    const _Float16* __restrict__ cin,
    const _Float16* __restrict__ wpk,
    const float* __restrict__ alpha, const float* __restrict__ beta,
    _Float16* __restrict__ o0, _Float16* __restrict__ o1,
    _Float16* __restrict__ o2, _Float16* __restrict__ o3,
    _Float16* __restrict__ o4) {
  const int NCHUNK = (MODE == 0) ? 14 : 4;
  __shared__ _Float16 hsh[6 * 66 * 36];  // [row6][col66][c-pad36]
  __shared__ float alsh[32], besh[32];
  int tid = threadIdx.x;
  int b = blockIdx.y, r0 = blockIdx.x * 4;
  if (MODE == 0 && tid < 32) { alsh[tid] = alpha[tid]; besh[tid] = beta[tid]; }
  __syncthreads();
  for (int t = tid; t < 384; t += 256) {  // zero halo cols
    int row = t >> 6, colh = ((t & 63) >> 5) ? 65 : 0, c = t & 31;
    hsh[(row * 66 + colh) * 36 + c] = (_Float16)0.f;
  }
  for (int t = tid; t < 32 * 384; t += 256) {
    int c = t / 384, p = t % 384;
    int row = p >> 6, col = p & 63;
    int rg = r0 + row - 1;
    float val = 0.f;
    if ((unsigned)rg < 64u) {
      if (MODE == 0)
        val = xin[((size_t)b * 64 + ch0 + c) * HW + (rg << 6) + col] * alsh[c] + besh[c];
      else
        val = (float)(cin[((size_t)b * 32 + c) * HW + (rg << 6) + col]);
    }
    hsh[((size_t)row * 66 + col + 1) * 36 + c] = (_Float16)val;
  }
  __syncthreads();
  int w = tid >> 6, l = tid & 63;
  int ln = l & 15, g = l >> 4;
  // cache B-fragments (h) for this wave's row, 4 col-tiles x 9 taps
  H8 bfr[4][9];
  #pragma unroll
  for (int pf = 0; pf < 4; pf++)
    #pragma unroll
    for (int dyi = 0; dyi < 3; dyi++)
      #pragma unroll
      for (int dxi = 0; dxi < 3; dxi++) {
        const _Float16* p = &hsh[(((size_t)(w + dyi)) * 66 + pf * 16 + ln + dxi) * 36 + 4 * g];
        H8 f;
        f.q[0] = *(const ushort4*)p;
        f.q[1] = *(const ushort4*)(p + 16);
        bfr[pf][dyi * 3 + dxi] = f;
      }
  const _Float16* wb = wpk + ((MODE == 1) ? (size_t)b * NCHUNK * 9 * 64 * 8 : 0);
  for (int chunk = 0; chunk < NCHUNK; chunk++) {
    H8 af[9];
    #pragma unroll
    for (int t = 0; t < 9; t++)
      af[t].u4 = *(const uint4*)(wb + (((size_t)chunk * 9 + t) * 64 + l) * 8);
    _Float16* ob; int Cb, ol0;
    if (MODE == 0) {
      if (chunk < 2)       { ob = o0; Cb = 32; ol0 = chunk * 16; }
      else if (chunk < 6)  { ob = o1; Cb = 64; ol0 = (chunk - 2) * 16; }
      else if (chunk < 8)  { ob = o2; Cb = 32; ol0 = (chunk - 6) * 16; }
      else if (chunk < 12) { ob = o3; Cb = 64; ol0 = (chunk - 8) * 16; }
      else                 { ob = o4; Cb = 32; ol0 = (chunk - 12) * 16; }
    } else { ob = o0; Cb = 64; ol0 = chunk * 16; }
    #pragma unroll
    for (int pf = 0; pf < 4; pf++) {
      f32x4 acc = {0.f, 0.f, 0.f, 0.f};
      #pragma unroll
      for (int t = 0; t < 9; t++)
        acc = __builtin_amdgcn_mfma_f32_16x16x32_f16(af[t].v, bfr[pf][t].v, acc, 0, 0, 0);
      int px = ((r0 + w) << 6) + pf * 16 + ln;
      #pragma unroll
      for (int j = 0; j < 4; j++) {
        int o = ol0 + 4 * g + j;
        ob[((size_t)b * Cb + o) * HW + px] = (_Float16)acc[j];
      }
    }
  }
}

// ---------------- attn k=3 partials (fp16 inputs) ----------------
__global__ __launch_bounds__(256) void attn1_partial_kernel(
    const _Float16* __restrict__ y1, const _Float16* __restrict__ y2,
    float* __restrict__ part) {
  int rc = blockIdx.x / 7, rg = blockIdx.x % 7;
  int b = blockIdx.y;
  __shared__ float s1[32][65];
  __shared__ float s2[64][65];
  int tid = threadIdx.x;
  int o = tid >> 2, i0 = (tid & 3) * 8;
  int col = tid & 63, rw = tid >> 6;
  float acc[8][3] = {};
  const _Float16* y1b = y1 + (size_t)b * 32 * HW;
  const _Float16* y2b = y2 + (size_t)b * 64 * HW;
  for (int j = 0; j < 3; j++) {
    int r = rc + 9 * rg + 3 * j;
    __syncthreads();
    for (int c = rw; c < 32; c += 4) s1[c][col] = (float)(y1b[(size_t)c * HW + (r << 6) + col]);
    for (int c = rw; c < 64; c += 4) s2[c][col] = (float)(y2b[(size_t)c * HW + (r << 6) + col]);
    __syncthreads();
    for (int c3 = 0; c3 < 21; c3++) {
      #pragma unroll
      for (int cc = 0; cc < 3; cc++) {
        int c = 3 * c3 + cc;
        float yo = s2[o][c];
        #pragma unroll
        for (int ii = 0; ii < 8; ii++) acc[ii][cc] += s1[i0 + ii][c] * yo;
      }
    }
  }
  size_t base = ((size_t)rg * 32 + b) * 2048 + o * 32 + i0;
  for (int ii = 0; ii < 8; ii++)
    #pragma unroll
    for (int cc = 0; cc < 3; cc++)
      part[(base + ii) * 9 + rc * 3 + cc] = acc[ii][cc];
}

// ---------------- attn k=1 partials (fp16 inputs) ----------------
__global__ __launch_bounds__(256) void attn2_partial_kernel(
    const _Float16* __restrict__ y1, const _Float16* __restrict__ y2,
    float* __restrict__ part) {
  int ps = blockIdx.x, b = blockIdx.y;
  __shared__ float s1[32][65];
  __shared__ float s2[64][65];
  int tid = threadIdx.x;
  int o = tid >> 2, i0 = (tid & 3) * 8;
  int col = tid & 63, rw = tid >> 6;
  float acc[8] = {};
  const _Float16* y1b = y1 + (size_t)b * 32 * HW + ps * 512;
  const _Float16* y2b = y2 + (size_t)b * 64 * HW + ps * 512;
  for (int t = 0; t < 8; t++) {
    __syncthreads();
    for (int c = rw; c < 32; c += 4) s1[c][col] = (float)(y1b[(size_t)c * HW + t * 64 + col]);
    for (int c = rw; c < 64; c += 4) s2[c][col] = (float)(y2b[(size_t)c * HW + t * 64 + col]);
    __syncthreads();
    #pragma unroll 8
    for (int p = 0; p < 64; p++) {
      float yo = s2[o][p];
      #pragma unroll
      for (int ii = 0; ii < 8; ii++) acc[ii] += s1[i0 + ii][p] * yo;
    }
  }
  size_t base = ((size_t)ps * 32 + b) * 2048 + o * 32 + i0;
  for (int ii = 0; ii < 8; ii++) part[base + ii] = acc[ii];
}

// ---------------- fused: reduce partials + softmax(a2) + ak = a2*(a1+aw) ----------------
__global__ __launch_bounds__(320) void fused_ak_kernel(
    const float* __restrict__ part1, const float* __restrict__ part2,
    const float* __restrict__ aw, float* __restrict__ akb) {
  int o = blockIdx.x, b = blockIdx.y;
  int tid = threadIdx.x;
  __shared__ float sm[33];
  if (tid < 32) {
    float s = 0.f;
    for (int ps = 0; ps < 8; ps++) s += part2[((size_t)ps * 32 + b) * 2048 + o * 32 + tid];
    sm[tid] = s * 0.17677669529663687f;  // 1/sqrt(32)
  }
  __syncthreads();
  if (tid == 0) {
    float mx = -1e30f;
    for (int k = 0; k < 32; k++) mx = fmaxf(mx, sm[k]);
    float sum = 0.f;
    for (int k = 0; k < 32; k++) { float e = expf(sm[k] - mx); sm[k] = e; sum += e; }
    sm[32] = 1.0f / sum;
  }
  __syncthreads();
  if (tid < 288) {
    int i = tid / 9, kk = tid % 9;
    size_t idx9 = (size_t)(o * 32 + i) * 9 + kk;
    float a1v = 0.f;
    for (int rg = 0; rg < 7; rg++)
      a1v += part1[((size_t)rg * 32 + b) * 2048 * 9 + idx9];
    a1v *= 0.05892556509887896f;  // 1/sqrt(288)
    float a2v = sm[i] * sm[32];
    akb[(((size_t)b * 64 + o) * 32 + i) * 9 + kk] = a2v * (a1v + aw[idx9]);
  }
}

// ---------------- output batchnorm affine + branch combine ----------------
__global__ __launch_bounds__(256) void finalize_kernel(
    const _Float16* __restrict__ v, const float* __restrict__ vmean,
    const float* __restrict__ vrstd, const float* __restrict__ a_post, int branch, int mode,
    float* __restrict__ acc, float* __restrict__ ysave,
    const float* __restrict__ x, const float* __restrict__ cm, float* __restrict__ out) {
  size_t idx = (size_t)blockIdx.x * 256 + threadIdx.x;  // B*64*HW
  int o = (int)((idx >> 12) & 63);
  float ap = a_post[branch];
  float ga = 0.5f * vrstd[o] + 0.6f * ap;
  float gb = -0.5f * vmean[o] * vrstd[o];
  float yv = ga * (float)(v[idx]) + gb;
  if (mode == 0) acc[idx] = yv;
  else if (mode == 1) acc[idx] += yv;
  else if (mode == 2) ysave[idx] = yv;
  else out[idx] = 0.99f * cm[0] * x[idx] + (acc[idx] + ysave[idx] * yv) * 0.5773502691896258f;
}

extern "C" void kernel_launch(void* const* d_in, const int* in_sizes, int n_in,
                              void* d_out, int out_size, void* d_ws, size_t ws_size,
                              hipStream_t stream) {
  const float* x      = (const float*)d_in[0];
  const float* wk1c1  = (const float*)d_in[1];
  const float* wk1c2  = (const float*)d_in[2];
  const float* wk2c1  = (const float*)d_in[3];
  const float* wk2c2  = (const float*)d_in[4];
  const float* wconv  = (const float*)d_in[5];
  const float* attn_w = (const float*)d_in[6];
  const float* a_pre  = (const float*)d_in[7];
  const float* a_post = (const float*)d_in[8];
  const float* cm     = (const float*)d_in[9];
  float* out = (float*)d_out;

  float* ws = (float*)d_ws;
  _Float16* y1a  = (_Float16*)(ws);             // 4,194,304 f16
  _Float16* y1b  = (_Float16*)(ws + 2097152);   // 8,388,608 f16
  _Float16* y2a  = (_Float16*)(ws + 6291456);   // 4,194,304 f16
  _Float16* y2b  = (_Float16*)(ws + 8388608);   // 8,388,608 f16
  _Float16* ccb  = (_Float16*)(ws + 12582912);  // 4,194,304 f16
  float* part1 = ws + 14680064;                 // 4,128,768 f32 (aliased w/ vbuf)
  _Float16* vbuf = (_Float16*)part1;            // 8,388,608 f16
  float* part2 = ws + 18874368;                 // 524,288
  float* akb   = ws + 19398656;                 // 589,824
  _Float16* wpk  = (_Float16*)(ws + 19988480);  // 258,048 f16
  _Float16* wdyn = (_Float16*)(ws + 20117504);  // 589,824 f16
  float* accb  = ws + 20412416;                 // 8,388,608
  float* ysave = ws + 28801024;                 // 8,388,608
  float* xmean = ws + 37189632;
  float* xrstd = xmean + 64;
  float* vmean = xmean + 128;
  float* vrstd = xmean + 192;
  float* alphab = xmean + 256;
  float* betab  = xmean + 288;
  float* pstat  = xmean + 320;  // 1024

  bn_partial_kernel<float><<<dim3(64, 8), 256, 0, stream>>>(x, 64, pstat);
  bn_reduce_kernel<<<1, 64, 0, stream>>>(pstat, 32.f * HW, xmean, xrstd);
  pack_static_kernel<<<1008, 256, 0, stream>>>(wk1c1, wk1c2, wk2c1, wk2c2, wconv, wpk);

  for (int br = 0; br < 4; br++) {
    int ch0 = (br & 1) * 32;
    coeffs_kernel<<<1, 32, 0, stream>>>(xmean, xrstd, ch0, a_pre, br, alphab, betab);

    conv_mfma_kernel<0><<<dim3(16, 32), 256, 0, stream>>>(
        x, ch0, nullptr, wpk + (size_t)br * 64512, alphab, betab,
        y1a, y1b, y2a, y2b, ccb);

    attn1_partial_kernel<<<dim3(21, 32), 256, 0, stream>>>(y1a, y1b, part1);
    attn2_partial_kernel<<<dim3(8, 32), 256, 0, stream>>>(y2a, y2b, part2);
    fused_ak_kernel<<<dim3(64, 32), 320, 0, stream>>>(
        part1, part2, attn_w + (size_t)br * 64 * 288, akb);

    pack_dyn_kernel<<<2304, 256, 0, stream>>>(akb, wdyn);
    conv_mfma_kernel<1><<<dim3(16, 32), 256, 0, stream>>>(
        nullptr, 0, ccb, wdyn, nullptr, nullptr,
        vbuf, nullptr, nullptr, nullptr, nullptr);

    bn_partial_kernel<_Float16><<<dim3(64, 8), 256, 0, stream>>>(vbuf, 64, pstat);
    bn_reduce_kernel<<<1, 64, 0, stream>>>(pstat, 32.f * HW, vmean, vrstd);
    finalize_kernel<<<32768, 256, 0, stream>>>(
        vbuf, vmean, vrstd, a_post, br, br, accb, ysave, x, cm, out);
  }
}

// Round 5
// 785.852 us; speedup vs baseline: 9.2827x; 1.1641x over previous
//
#include <hip/hip_runtime.h>
#include <math.h>

#define HW 4096
#define BB 32
#define EPSV 1e-5f

typedef _Float16 half8 __attribute__((ext_vector_type(8)));
typedef float f32x4 __attribute__((ext_vector_type(4)));
union H8 { half8 v; ushort4 q[2]; uint4 u4; };

__device__ __forceinline__ float tofloat(const float& v) { return v; }
__device__ __forceinline__ float tofloat(const _Float16& v) { return (float)v; }

// ---------------- bn stats: partial + reduce ----------------
template <typename T>
__global__ __launch_bounds__(256) void bn_partial_kernel(
    const T* __restrict__ x, int C, float* __restrict__ pstat) {
  int c = blockIdx.x, s = blockIdx.y;
  int tid = threadIdx.x;
  float sm = 0.f, s2 = 0.f;
  for (int b = s * 4; b < s * 4 + 4; b++) {
    const T* p = x + ((size_t)b * C + c) * HW;
    for (int i = tid; i < HW; i += 256) { float t = tofloat(p[i]); sm += t; s2 += t * t; }
  }
  __shared__ float sh[2][256];
  sh[0][tid] = sm; sh[1][tid] = s2;
  __syncthreads();
  for (int off = 128; off > 0; off >>= 1) {
    if (tid < off) { sh[0][tid] += sh[0][tid + off]; sh[1][tid] += sh[1][tid + off]; }
    __syncthreads();
  }
  if (tid == 0) {
    pstat[((size_t)s * 64 + c) * 2] = sh[0][0];
    pstat[((size_t)s * 64 + c) * 2 + 1] = sh[1][0];
  }
}

__global__ void bn_reduce_kernel(const float* __restrict__ pstat, float N,
                                 float* __restrict__ mean, float* __restrict__ rstd) {
  int c = threadIdx.x;  // 64
  float s = 0.f, s2 = 0.f;
  for (int k = 0; k < 8; k++) {
    s += pstat[((size_t)k * 64 + c) * 2];
    s2 += pstat[((size_t)k * 64 + c) * 2 + 1];
  }
  float m = s / N;
  mean[c] = m;
  rstd[c] = rsqrtf(s2 / N - m * m + EPSV);
}

// ---------------- fold batchnorm+shortcut into per-channel affine ----------------
__global__ void coeffs_kernel(const float* __restrict__ mean, const float* __restrict__ rstd,
                              int ch0, const float* __restrict__ a_pre, int branch,
                              float* __restrict__ alpha, float* __restrict__ beta) {
  int c = threadIdx.x;  // 32
  float ap = a_pre[branch];
  float r = rstd[ch0 + c], m = mean[ch0 + c];
  alpha[c] = 0.5f * r + 0.01f * ap;
  beta[c]  = -0.5f * m * r;
}

// ---------------- pack static conv weights into MFMA A-fragment order ----------------
// wpk[br][chunk14][tap9][lane64][j8]; A row o = chunk*16+(lane&15); k(c) = j<4 ? 4g+j : 16+4g+j-4
__global__ __launch_bounds__(256) void pack_static_kernel(
    const float* __restrict__ wk1c1, const float* __restrict__ wk1c2,
    const float* __restrict__ wk2c1, const float* __restrict__ wk2c2,
    const float* __restrict__ wconv, _Float16* __restrict__ wpk) {
  int idx = blockIdx.x * 256 + threadIdx.x;  // 258048
  int j = idx & 7, lane = (idx >> 3) & 63;
  int tap = (idx >> 9) % 9;
  int chunk = (idx / 4608) % 14;
  int br = idx / 64512;
  int g = lane >> 4;
  int c = (j < 4) ? 4 * g + j : 16 + 4 * g + (j - 4);
  const float* src; int ol0;
  if (chunk < 2)       { src = wk1c1 + (size_t)br * 32 * 288; ol0 = chunk * 16; }
  else if (chunk < 6)  { src = wk1c2 + (size_t)br * 64 * 288; ol0 = (chunk - 2) * 16; }
  else if (chunk < 8)  { src = wk2c1 + (size_t)br * 32 * 288; ol0 = (chunk - 6) * 16; }
  else if (chunk < 12) { src = wk2c2 + (size_t)br * 64 * 288; ol0 = (chunk - 8) * 16; }
  else                 { src = wconv + (size_t)br * 32 * 288; ol0 = (chunk - 12) * 16; }
  int o = ol0 + (lane & 15);
  wpk[idx] = (_Float16)(src[((size_t)o * 32 + c) * 9 + tap]);
}

// ---------------- MFMA conv: 9 shifted K=32 GEMMs; MODE0 = 5 static convs, MODE1 = dynamic ----------------
template <int MODE>
__global__ __launch_bounds__(256) void conv_mfma_kernel(
    const float* __restrict__ xin, int ch0,
    const _Float16* __restrict__ cin,
    const _Float16* __restrict__ wpk,
    const float* __restrict__ alpha, const float* __restrict__ beta,
    _Float16* __restrict__ o0, _Float16* __restrict__ o1,
    _Float16* __restrict__ o2, _Float16* __restrict__ o3,
    _Float16* __restrict__ o4) {
  const int NCHUNK = (MODE == 0) ? 14 : 4;
  __shared__ _Float16 hsh[6 * 66 * 36];  // [row6][col66][c-pad36]
  __shared__ float alsh[32], besh[32];
  int tid = threadIdx.x;
  int b = blockIdx.y, r0 = blockIdx.x * 4;
  if (MODE == 0 && tid < 32) { alsh[tid] = alpha[tid]; besh[tid] = beta[tid]; }
  __syncthreads();
  for (int t = tid; t < 384; t += 256) {  // zero halo cols
    int row = t >> 6, colh = ((t & 63) >> 5) ? 65 : 0, c = t & 31;
    hsh[(row * 66 + colh) * 36 + c] = (_Float16)0.f;
  }
  for (int t = tid; t < 32 * 384; t += 256) {
    int c = t / 384, p = t % 384;
    int row = p >> 6, col = p & 63;
    int rg = r0 + row - 1;
    float val = 0.f;
    if ((unsigned)rg < 64u) {
      if (MODE == 0)
        val = xin[((size_t)b * 64 + ch0 + c) * HW + (rg << 6) + col] * alsh[c] + besh[c];
      else
        val = (float)(cin[((size_t)b * 32 + c) * HW + (rg << 6) + col]);
    }
    hsh[((size_t)row * 66 + col + 1) * 36 + c] = (_Float16)val;
  }
  __syncthreads();
  int w = tid >> 6, l = tid & 63;
  int ln = l & 15, g = l >> 4;
  // cache B-fragments (h) for this wave's row, 4 col-tiles x 9 taps
  H8 bfr[4][9];
  #pragma unroll
  for (int pf = 0; pf < 4; pf++)
    #pragma unroll
    for (int dyi = 0; dyi < 3; dyi++)
      #pragma unroll
      for (int dxi = 0; dxi < 3; dxi++) {
        const _Float16* p = &hsh[(((size_t)(w + dyi)) * 66 + pf * 16 + ln + dxi) * 36 + 4 * g];
        H8 f;
        f.q[0] = *(const ushort4*)p;
        f.q[1] = *(const ushort4*)(p + 16);
        bfr[pf][dyi * 3 + dxi] = f;
      }
  const _Float16* wb = wpk + ((MODE == 1) ? (size_t)b * NCHUNK * 9 * 64 * 8 : 0);
  for (int chunk = 0; chunk < NCHUNK; chunk++) {
    H8 af[9];
    #pragma unroll
    for (int t = 0; t < 9; t++)
      af[t].u4 = *(const uint4*)(wb + (((size_t)chunk * 9 + t) * 64 + l) * 8);
    _Float16* ob; int Cb, ol0;
    if (MODE == 0) {
      if (chunk < 2)       { ob = o0; Cb = 32; ol0 = chunk * 16; }
      else if (chunk < 6)  { ob = o1; Cb = 64; ol0 = (chunk - 2) * 16; }
      else if (chunk < 8)  { ob = o2; Cb = 32; ol0 = (chunk - 6) * 16; }
      else if (chunk < 12) { ob = o3; Cb = 64; ol0 = (chunk - 8) * 16; }
      else                 { ob = o4; Cb = 32; ol0 = (chunk - 12) * 16; }
    } else { ob = o0; Cb = 64; ol0 = chunk * 16; }
    #pragma unroll
    for (int pf = 0; pf < 4; pf++) {
      f32x4 acc = {0.f, 0.f, 0.f, 0.f};
      #pragma unroll
      for (int t = 0; t < 9; t++)
        acc = __builtin_amdgcn_mfma_f32_16x16x32_f16(af[t].v, bfr[pf][t].v, acc, 0, 0, 0);
      int px = ((r0 + w) << 6) + pf * 16 + ln;
      #pragma unroll
      for (int j = 0; j < 4; j++) {
        int o = ol0 + 4 * g + j;
        ob[((size_t)b * Cb + o) * HW + px] = (_Float16)acc[j];
      }
    }
  }
}

// ---------------- attn k=3 partials (fp16 inputs) ----------------
__global__ __launch_bounds__(256) void attn1_partial_kernel(
    const _Float16* __restrict__ y1, const _Float16* __restrict__ y2,
    float* __restrict__ part) {
  int rc = blockIdx.x / 7, rg = blockIdx.x % 7;
  int b = blockIdx.y;
  __shared__ float s1[32][65];
  __shared__ float s2[64][65];
  int tid = threadIdx.x;
  int o = tid >> 2, i0 = (tid & 3) * 8;
  int col = tid & 63, rw = tid >> 6;
  float acc[8][3] = {};
  const _Float16* y1b = y1 + (size_t)b * 32 * HW;
  const _Float16* y2b = y2 + (size_t)b * 64 * HW;
  for (int j = 0; j < 3; j++) {
    int r = rc + 9 * rg + 3 * j;
    __syncthreads();
    for (int c = rw; c < 32; c += 4) s1[c][col] = (float)(y1b[(size_t)c * HW + (r << 6) + col]);
    for (int c = rw; c < 64; c += 4) s2[c][col] = (float)(y2b[(size_t)c * HW + (r << 6) + col]);
    __syncthreads();
    for (int c3 = 0; c3 < 21; c3++) {
      #pragma unroll
      for (int cc = 0; cc < 3; cc++) {
        int c = 3 * c3 + cc;
        float yo = s2[o][c];
        #pragma unroll
        for (int ii = 0; ii < 8; ii++) acc[ii][cc] += s1[i0 + ii][c] * yo;
      }
    }
  }
  size_t base = ((size_t)rg * 32 + b) * 2048 + o * 32 + i0;
  for (int ii = 0; ii < 8; ii++)
    #pragma unroll
    for (int cc = 0; cc < 3; cc++)
      part[(base + ii) * 9 + rc * 3 + cc] = acc[ii][cc];
}

// ---------------- attn k=1 partials: one 64-px tile per block (split-K=64) ----------------
__global__ __launch_bounds__(256) void attn2_partial_kernel(
    const _Float16* __restrict__ y1, const _Float16* __restrict__ y2,
    float* __restrict__ part) {
  int ps = blockIdx.x, b = blockIdx.y;  // ps 0..63
  __shared__ float s1[32][65];
  __shared__ float s2[64][65];
  int tid = threadIdx.x;
  int o = tid >> 2, i0 = (tid & 3) * 8;
  int col = tid & 63, rw = tid >> 6;
  const _Float16* y1b = y1 + (size_t)b * 32 * HW + ps * 64;
  const _Float16* y2b = y2 + (size_t)b * 64 * HW + ps * 64;
  for (int c = rw; c < 32; c += 4) s1[c][col] = (float)(y1b[(size_t)c * HW + col]);
  for (int c = rw; c < 64; c += 4) s2[c][col] = (float)(y2b[(size_t)c * HW + col]);
  __syncthreads();
  float acc[8] = {};
  #pragma unroll 8
  for (int p = 0; p < 64; p++) {
    float yo = s2[o][p];
    #pragma unroll
    for (int ii = 0; ii < 8; ii++) acc[ii] += s1[i0 + ii][p] * yo;
  }
  size_t base = ((size_t)ps * 32 + b) * 2048 + o * 32 + i0;
  for (int ii = 0; ii < 8; ii++) part[base + ii] = acc[ii];
}

// ---------------- fused: reduce partials + softmax(a2) + ak + pack to MFMA order ----------------
__global__ __launch_bounds__(320) void fused_ak_kernel(
    const float* __restrict__ part1, const float* __restrict__ part2,
    const float* __restrict__ aw, _Float16* __restrict__ wdyn) {
  int o = blockIdx.x, b = blockIdx.y;
  int tid = threadIdx.x;
  __shared__ float sm[33];
  if (tid < 32) {
    float s = 0.f;
    for (int ps = 0; ps < 64; ps++) s += part2[((size_t)ps * 32 + b) * 2048 + o * 32 + tid];
    sm[tid] = s * 0.17677669529663687f;  // 1/sqrt(32)
  }
  __syncthreads();
  if (tid == 0) {
    float mx = -1e30f;
    for (int k = 0; k < 32; k++) mx = fmaxf(mx, sm[k]);
    float sum = 0.f;
    for (int k = 0; k < 32; k++) { float e = expf(sm[k] - mx); sm[k] = e; sum += e; }
    sm[32] = 1.0f / sum;
  }
  __syncthreads();
  if (tid < 288) {
    int i = tid / 9, kk = tid % 9;
    size_t idx9 = (size_t)(o * 32 + i) * 9 + kk;
    float a1v = 0.f;
    for (int rg = 0; rg < 7; rg++)
      a1v += part1[((size_t)rg * 32 + b) * 2048 * 9 + idx9];
    a1v *= 0.05892556509887896f;  // 1/sqrt(288)
    float akv = sm[i] * sm[32] * (a1v + aw[idx9]);
    // pack directly into MFMA A-fragment order: wdyn[b][chunk][tap][lane][j]
    int chunk = o >> 4;
    int g = (i & 15) >> 2;
    int j = (i & 3) + ((i >= 16) ? 4 : 0);
    int lane = (g << 4) | (o & 15);
    wdyn[((((size_t)b * 4 + chunk) * 9 + kk) * 64 + lane) * 8 + j] = (_Float16)akv;
  }
}

// ---------------- output batchnorm affine + branch combine ----------------
__global__ __launch_bounds__(256) void finalize_kernel(
    const _Float16* __restrict__ v, const float* __restrict__ vmean,
    const float* __restrict__ vrstd, const float* __restrict__ a_post, int branch, int mode,
    float* __restrict__ acc, float* __restrict__ ysave,
    const float* __restrict__ x, const float* __restrict__ cm, float* __restrict__ out) {
  size_t idx = (size_t)blockIdx.x * 256 + threadIdx.x;  // B*64*HW
  int o = (int)((idx >> 12) & 63);
  float ap = a_post[branch];
  float ga = 0.5f * vrstd[o] + 0.6f * ap;
  float gb = -0.5f * vmean[o] * vrstd[o];
  float yv = ga * (float)(v[idx]) + gb;
  if (mode == 0) acc[idx] = yv;
  else if (mode == 1) acc[idx] += yv;
  else if (mode == 2) ysave[idx] = yv;
  else out[idx] = 0.99f * cm[0] * x[idx] + (acc[idx] + ysave[idx] * yv) * 0.5773502691896258f;
}

extern "C" void kernel_launch(void* const* d_in, const int* in_sizes, int n_in,
                              void* d_out, int out_size, void* d_ws, size_t ws_size,
                              hipStream_t stream) {
  const float* x      = (const float*)d_in[0];
  const float* wk1c1  = (const float*)d_in[1];
  const float* wk1c2  = (const float*)d_in[2];
  const float* wk2c1  = (const float*)d_in[3];
  const float* wk2c2  = (const float*)d_in[4];
  const float* wconv  = (const float*)d_in[5];
  const float* attn_w = (const float*)d_in[6];
  const float* a_pre  = (const float*)d_in[7];
  const float* a_post = (const float*)d_in[8];
  const float* cm     = (const float*)d_in[9];
  float* out = (float*)d_out;

  float* ws = (float*)d_ws;
  _Float16* y1a  = (_Float16*)(ws);             // 4,194,304 f16
  _Float16* y1b  = (_Float16*)(ws + 2097152);   // 8,388,608 f16
  _Float16* y2a  = (_Float16*)(ws + 6291456);   // 4,194,304 f16
  _Float16* y2b  = (_Float16*)(ws + 8388608);   // 8,388,608 f16
  _Float16* ccb  = (_Float16*)(ws + 12582912);  // 4,194,304 f16
  float* part1 = ws + 14680064;                 // 4,128,768 f32 (aliases vbuf slot)
  _Float16* vbuf = (_Float16*)part1;            // 8,388,608 f16
  float* part2 = ws + 2097152;                  // 4,194,304 f32 (aliases y1b slot; dead after attn1)
  _Float16* wpk  = (_Float16*)(ws + 19988480);  // 258,048 f16
  _Float16* wdyn = (_Float16*)(ws + 20117504);  // 589,824 f16
  float* accb  = ws + 20412416;                 // 8,388,608
  float* ysave = ws + 28801024;                 // 8,388,608
  float* xmean = ws + 37189632;
  float* xrstd = xmean + 64;
  float* vmean = xmean + 128;
  float* vrstd = xmean + 192;
  float* alphab = xmean + 256;
  float* betab  = xmean + 288;
  float* pstat  = xmean + 320;  // 1024

  bn_partial_kernel<float><<<dim3(64, 8), 256, 0, stream>>>(x, 64, pstat);
  bn_reduce_kernel<<<1, 64, 0, stream>>>(pstat, 32.f * HW, xmean, xrstd);
  pack_static_kernel<<<1008, 256, 0, stream>>>(wk1c1, wk1c2, wk2c1, wk2c2, wconv, wpk);

  for (int br = 0; br < 4; br++) {
    int ch0 = (br & 1) * 32;
    coeffs_kernel<<<1, 32, 0, stream>>>(xmean, xrstd, ch0, a_pre, br, alphab, betab);

    conv_mfma_kernel<0><<<dim3(16, 32), 256, 0, stream>>>(
        x, ch0, nullptr, wpk + (size_t)br * 64512, alphab, betab,
        y1a, y1b, y2a, y2b, ccb);

    // attn1 first (reads y1a/y1b), then attn2 (part2 overwrites the y1b slot)
    attn1_partial_kernel<<<dim3(21, 32), 256, 0, stream>>>(y1a, y1b, part1);
    attn2_partial_kernel<<<dim3(64, 32), 256, 0, stream>>>(y2a, y2b, part2);
    fused_ak_kernel<<<dim3(64, 32), 320, 0, stream>>>(
        part1, part2, attn_w + (size_t)br * 64 * 288, wdyn);

    conv_mfma_kernel<1><<<dim3(16, 32), 256, 0, stream>>>(
        nullptr, 0, ccb, wdyn, nullptr, nullptr,
        vbuf, nullptr, nullptr, nullptr, nullptr);

    bn_partial_kernel<_Float16><<<dim3(64, 8), 256, 0, stream>>>(vbuf, 64, pstat);
    bn_reduce_kernel<<<1, 64, 0, stream>>>(pstat, 32.f * HW, vmean, vrstd);
    finalize_kernel<<<32768, 256, 0, stream>>>(
        vbuf, vmean, vrstd, a_post, br, br, accb, ysave, x, cm, out);
  }
}

// Round 6
// 750.454 us; speedup vs baseline: 9.7205x; 1.0472x over previous
//
#include <hip/hip_runtime.h>
#include <math.h>

#define HW 4096
#define BB 32
#define EPSV 1e-5f

typedef _Float16 half8 __attribute__((ext_vector_type(8)));
typedef float f32x4 __attribute__((ext_vector_type(4)));
union H8 { half8 v; ushort4 q[2]; uint4 u4; };

__device__ __forceinline__ float tofloat(const float& v) { return v; }
__device__ __forceinline__ float tofloat(const _Float16& v) { return (float)v; }

// ---------------- bn stats: partial + reduce ----------------
template <typename T>
__global__ __launch_bounds__(256) void bn_partial_kernel(
    const T* __restrict__ x, int C, float* __restrict__ pstat) {
  int c = blockIdx.x, s = blockIdx.y;
  int tid = threadIdx.x;
  float sm = 0.f, s2 = 0.f;
  for (int b = s * 4; b < s * 4 + 4; b++) {
    const T* p = x + ((size_t)b * C + c) * HW;
    for (int i = tid; i < HW; i += 256) { float t = tofloat(p[i]); sm += t; s2 += t * t; }
  }
  __shared__ float sh[2][256];
  sh[0][tid] = sm; sh[1][tid] = s2;
  __syncthreads();
  for (int off = 128; off > 0; off >>= 1) {
    if (tid < off) { sh[0][tid] += sh[0][tid + off]; sh[1][tid] += sh[1][tid + off]; }
    __syncthreads();
  }
  if (tid == 0) {
    pstat[((size_t)s * 64 + c) * 2] = sh[0][0];
    pstat[((size_t)s * 64 + c) * 2 + 1] = sh[1][0];
  }
}

__global__ void bn_reduce_kernel(const float* __restrict__ pstat, float N,
                                 float* __restrict__ mean, float* __restrict__ rstd) {
  int c = threadIdx.x;  // 64
  float s = 0.f, s2 = 0.f;
  for (int k = 0; k < 8; k++) {
    s += pstat[((size_t)k * 64 + c) * 2];
    s2 += pstat[((size_t)k * 64 + c) * 2 + 1];
  }
  float m = s / N;
  mean[c] = m;
  rstd[c] = rsqrtf(s2 / N - m * m + EPSV);
}

// ---------------- fold batchnorm+shortcut into per-channel affine ----------------
__global__ void coeffs_kernel(const float* __restrict__ mean, const float* __restrict__ rstd,
                              int ch0, const float* __restrict__ a_pre, int branch,
                              float* __restrict__ alpha, float* __restrict__ beta) {
  int c = threadIdx.x;  // 32
  float ap = a_pre[branch];
  float r = rstd[ch0 + c], m = mean[ch0 + c];
  alpha[c] = 0.5f * r + 0.01f * ap;
  beta[c]  = -0.5f * m * r;
}

// ---------------- pack static conv weights into MFMA A-fragment order ----------------
// wpk[br][chunk14][tap9][lane64][j8]; A row o = chunk*16+(lane&15); k(c) = j<4 ? 4g+j : 16+4g+j-4
__global__ __launch_bounds__(256) void pack_static_kernel(
    const float* __restrict__ wk1c1, const float* __restrict__ wk1c2,
    const float* __restrict__ wk2c1, const float* __restrict__ wk2c2,
    const float* __restrict__ wconv, _Float16* __restrict__ wpk) {
  int idx = blockIdx.x * 256 + threadIdx.x;  // 258048
  int j = idx & 7, lane = (idx >> 3) & 63;
  int tap = (idx >> 9) % 9;
  int chunk = (idx / 4608) % 14;
  int br = idx / 64512;
  int g = lane >> 4;
  int c = (j < 4) ? 4 * g + j : 16 + 4 * g + (j - 4);
  const float* src; int ol0;
  if (chunk < 2)       { src = wk1c1 + (size_t)br * 32 * 288; ol0 = chunk * 16; }
  else if (chunk < 6)  { src = wk1c2 + (size_t)br * 64 * 288; ol0 = (chunk - 2) * 16; }
  else if (chunk < 8)  { src = wk2c1 + (size_t)br * 32 * 288; ol0 = (chunk - 6) * 16; }
  else if (chunk < 12) { src = wk2c2 + (size_t)br * 64 * 288; ol0 = (chunk - 8) * 16; }
  else                 { src = wconv + (size_t)br * 32 * 288; ol0 = (chunk - 12) * 16; }
  int o = ol0 + (lane & 15);
  wpk[idx] = (_Float16)(src[((size_t)o * 32 + c) * 9 + tap]);
}

// ---------------- MFMA conv: 9 shifted K=32 GEMMs; MODE0 = 5 static convs, MODE1 = dynamic ----------------
template <int MODE>
__global__ __launch_bounds__(256) void conv_mfma_kernel(
    const float* __restrict__ xin, int ch0,
    const _Float16* __restrict__ cin,
    const _Float16* __restrict__ wpk,
    const float* __restrict__ alpha, const float* __restrict__ beta,
    _Float16* __restrict__ o0, _Float16* __restrict__ o1,
    _Float16* __restrict__ o2, _Float16* __restrict__ o3,
    _Float16* __restrict__ o4) {
  const int NCHUNK = (MODE == 0) ? 14 : 4;
  __shared__ _Float16 hsh[6 * 66 * 36];  // [row6][col66][c-pad36]
  __shared__ float alsh[32], besh[32];
  int tid = threadIdx.x;
  int b = blockIdx.y, r0 = blockIdx.x * 4;
  if (MODE == 0 && tid < 32) { alsh[tid] = alpha[tid]; besh[tid] = beta[tid]; }
  __syncthreads();
  for (int t = tid; t < 384; t += 256) {  // zero halo cols
    int row = t >> 6, colh = ((t & 63) >> 5) ? 65 : 0, c = t & 31;
    hsh[(row * 66 + colh) * 36 + c] = (_Float16)0.f;
  }
  for (int t = tid; t < 32 * 384; t += 256) {
    int c = t / 384, p = t % 384;
    int row = p >> 6, col = p & 63;
    int rg = r0 + row - 1;
    float val = 0.f;
    if ((unsigned)rg < 64u) {
      if (MODE == 0)
        val = xin[((size_t)b * 64 + ch0 + c) * HW + (rg << 6) + col] * alsh[c] + besh[c];
      else
        val = (float)(cin[((size_t)b * 32 + c) * HW + (rg << 6) + col]);
    }
    hsh[((size_t)row * 66 + col + 1) * 36 + c] = (_Float16)val;
  }
  __syncthreads();
  int w = tid >> 6, l = tid & 63;
  int ln = l & 15, g = l >> 4;
  // cache B-fragments (h) for this wave's row, 4 col-tiles x 9 taps
  H8 bfr[4][9];
  #pragma unroll
  for (int pf = 0; pf < 4; pf++)
    #pragma unroll
    for (int dyi = 0; dyi < 3; dyi++)
      #pragma unroll
      for (int dxi = 0; dxi < 3; dxi++) {
        const _Float16* p = &hsh[(((size_t)(w + dyi)) * 66 + pf * 16 + ln + dxi) * 36 + 4 * g];
        H8 f;
        f.q[0] = *(const ushort4*)p;
        f.q[1] = *(const ushort4*)(p + 16);
        bfr[pf][dyi * 3 + dxi] = f;
      }
  const _Float16* wb = wpk + ((MODE == 1) ? (size_t)b * NCHUNK * 9 * 64 * 8 : 0);
  for (int chunk = 0; chunk < NCHUNK; chunk++) {
    H8 af[9];
    #pragma unroll
    for (int t = 0; t < 9; t++)
      af[t].u4 = *(const uint4*)(wb + (((size_t)chunk * 9 + t) * 64 + l) * 8);
    _Float16* ob; int Cb, ol0;
    if (MODE == 0) {
      if (chunk < 2)       { ob = o0; Cb = 32; ol0 = chunk * 16; }
      else if (chunk < 6)  { ob = o1; Cb = 64; ol0 = (chunk - 2) * 16; }
      else if (chunk < 8)  { ob = o2; Cb = 32; ol0 = (chunk - 6) * 16; }
      else if (chunk < 12) { ob = o3; Cb = 64; ol0 = (chunk - 8) * 16; }
      else                 { ob = o4; Cb = 32; ol0 = (chunk - 12) * 16; }
    } else { ob = o0; Cb = 64; ol0 = chunk * 16; }
    #pragma unroll
    for (int pf = 0; pf < 4; pf++) {
      f32x4 acc = {0.f, 0.f, 0.f, 0.f};
      #pragma unroll
      for (int t = 0; t < 9; t++)
        acc = __builtin_amdgcn_mfma_f32_16x16x32_f16(af[t].v, bfr[pf][t].v, acc, 0, 0, 0);
      int px = ((r0 + w) << 6) + pf * 16 + ln;
      #pragma unroll
      for (int j = 0; j < 4; j++) {
        int o = ol0 + 4 * g + j;
        ob[((size_t)b * Cb + o) * HW + px] = (_Float16)acc[j];
      }
    }
  }
}

// ---------------- attn k=3 partials: o-split, coalesced float4 writes ----------------
// grid (21, 32, 2): bx = rc*7+rg; bz = o-half. part1[bx][b][oh][cc][ol*32+i]
__global__ __launch_bounds__(256) void attn1_partial_kernel(
    const _Float16* __restrict__ y1, const _Float16* __restrict__ y2,
    float* __restrict__ part) {
  int rc = blockIdx.x / 7, rg = blockIdx.x % 7;
  int b = blockIdx.y, oh = blockIdx.z;
  __shared__ float s1[32][65];
  __shared__ float s2[32][65];
  int tid = threadIdx.x;
  int ol = tid >> 3;          // 0..31 (local o)
  int i0 = (tid & 7) * 4;     // 0,4,...,28
  int col = tid & 63, rw = tid >> 6;
  float acc[4][3] = {};
  const _Float16* y1b = y1 + (size_t)b * 32 * HW;
  const _Float16* y2b = y2 + ((size_t)b * 64 + oh * 32) * HW;
  for (int j = 0; j < 3; j++) {
    int r = rc + 9 * rg + 3 * j;
    __syncthreads();
    for (int c = rw; c < 32; c += 4) {
      s1[c][col] = (float)(y1b[(size_t)c * HW + (r << 6) + col]);
      s2[c][col] = (float)(y2b[(size_t)c * HW + (r << 6) + col]);
    }
    __syncthreads();
    for (int c3 = 0; c3 < 21; c3++) {
      #pragma unroll
      for (int cc = 0; cc < 3; cc++) {
        int c = 3 * c3 + cc;
        float yo = s2[ol][c];
        #pragma unroll
        for (int ii = 0; ii < 4; ii++) acc[ii][cc] += s1[i0 + ii][c] * yo;
      }
    }
  }
  size_t base = ((((size_t)blockIdx.x * 32 + b) * 2 + oh) * 3) * 1024 + ol * 32 + i0;
  #pragma unroll
  for (int cc = 0; cc < 3; cc++) {
    float4 v = {acc[0][cc], acc[1][cc], acc[2][cc], acc[3][cc]};
    *(float4*)&part[base + (size_t)cc * 1024] = v;
  }
}

// ---------------- attn k=1 partials: one 64-px tile per block (split-K=64) ----------------
__global__ __launch_bounds__(256) void attn2_partial_kernel(
    const _Float16* __restrict__ y1, const _Float16* __restrict__ y2,
    float* __restrict__ part) {
  int ps = blockIdx.x, b = blockIdx.y;  // ps 0..63
  __shared__ float s1[32][65];
  __shared__ float s2[64][65];
  int tid = threadIdx.x;
  int o = tid >> 2, i0 = (tid & 3) * 8;
  int col = tid & 63, rw = tid >> 6;
  const _Float16* y1b = y1 + (size_t)b * 32 * HW + ps * 64;
  const _Float16* y2b = y2 + (size_t)b * 64 * HW + ps * 64;
  for (int c = rw; c < 32; c += 4) s1[c][col] = (float)(y1b[(size_t)c * HW + col]);
  for (int c = rw; c < 64; c += 4) s2[c][col] = (float)(y2b[(size_t)c * HW + col]);
  __syncthreads();
  float acc[8] = {};
  #pragma unroll 8
  for (int p = 0; p < 64; p++) {
    float yo = s2[o][p];
    #pragma unroll
    for (int ii = 0; ii < 8; ii++) acc[ii] += s1[i0 + ii][p] * yo;
  }
  size_t base = ((size_t)ps * 32 + b) * 2048 + o * 32 + i0;
  for (int ii = 0; ii < 8; ii++) part[base + ii] = acc[ii];
}

// ---------------- fused: reduce partials + softmax(a2) + ak + pack to MFMA order ----------------
__global__ __launch_bounds__(320) void fused_ak_kernel(
    const float* __restrict__ part1, const float* __restrict__ part2,
    const float* __restrict__ aw, _Float16* __restrict__ wdyn) {
  int o = blockIdx.x, b = blockIdx.y;
  int tid = threadIdx.x;
  __shared__ float sm[33];
  if (tid < 32) {
    float s = 0.f;
    for (int ps = 0; ps < 64; ps++) s += part2[((size_t)ps * 32 + b) * 2048 + o * 32 + tid];
    sm[tid] = s * 0.17677669529663687f;  // 1/sqrt(32)
  }
  __syncthreads();
  if (tid == 0) {
    float mx = -1e30f;
    for (int k = 0; k < 32; k++) mx = fmaxf(mx, sm[k]);
    float sum = 0.f;
    for (int k = 0; k < 32; k++) { float e = expf(sm[k] - mx); sm[k] = e; sum += e; }
    sm[32] = 1.0f / sum;
  }
  __syncthreads();
  if (tid < 288) {
    int i = tid / 9, kk = tid % 9;
    int rc = kk / 3, cc = kk % 3;
    float a1v = 0.f;
    for (int rg = 0; rg < 7; rg++)
      a1v += part1[((((size_t)(rc * 7 + rg) * 32 + b) * 2 + (o >> 5)) * 3 + cc) * 1024 +
                   (o & 31) * 32 + i];
    a1v *= 0.05892556509887896f;  // 1/sqrt(288)
    float akv = sm[i] * sm[32] * (a1v + aw[(size_t)(o * 32 + i) * 9 + kk]);
    // pack directly into MFMA A-fragment order: wdyn[b][chunk][tap][lane][j]
    int chunk = o >> 4;
    int g = (i & 15) >> 2;
    int j = (i & 3) + ((i >= 16) ? 4 : 0);
    int lane = (g << 4) | (o & 15);
    wdyn[((((size_t)b * 4 + chunk) * 9 + kk) * 64 + lane) * 8 + j] = (_Float16)akv;
  }
}

// ---------------- output batchnorm affine + branch combine ----------------
__global__ __launch_bounds__(256) void finalize_kernel(
    const _Float16* __restrict__ v, const float* __restrict__ vmean,
    const float* __restrict__ vrstd, const float* __restrict__ a_post, int branch, int mode,
    float* __restrict__ acc, float* __restrict__ ysave,
    const float* __restrict__ x, const float* __restrict__ cm, float* __restrict__ out) {
  size_t idx = (size_t)blockIdx.x * 256 + threadIdx.x;  // B*64*HW
  int o = (int)((idx >> 12) & 63);
  float ap = a_post[branch];
  float ga = 0.5f * vrstd[o] + 0.6f * ap;
  float gb = -0.5f * vmean[o] * vrstd[o];
  float yv = ga * (float)(v[idx]) + gb;
  if (mode == 0) acc[idx] = yv;
  else if (mode == 1) acc[idx] += yv;
  else if (mode == 2) ysave[idx] = yv;
  else out[idx] = 0.99f * cm[0] * x[idx] + (acc[idx] + ysave[idx] * yv) * 0.5773502691896258f;
}

extern "C" void kernel_launch(void* const* d_in, const int* in_sizes, int n_in,
                              void* d_out, int out_size, void* d_ws, size_t ws_size,
                              hipStream_t stream) {
  const float* x      = (const float*)d_in[0];
  const float* wk1c1  = (const float*)d_in[1];
  const float* wk1c2  = (const float*)d_in[2];
  const float* wk2c1  = (const float*)d_in[3];
  const float* wk2c2  = (const float*)d_in[4];
  const float* wconv  = (const float*)d_in[5];
  const float* attn_w = (const float*)d_in[6];
  const float* a_pre  = (const float*)d_in[7];
  const float* a_post = (const float*)d_in[8];
  const float* cm     = (const float*)d_in[9];
  float* out = (float*)d_out;

  float* ws = (float*)d_ws;
  _Float16* y1a  = (_Float16*)(ws);             // 4,194,304 f16
  _Float16* y1b  = (_Float16*)(ws + 2097152);   // 8,388,608 f16
  _Float16* y2a  = (_Float16*)(ws + 6291456);   // 4,194,304 f16
  _Float16* y2b  = (_Float16*)(ws + 8388608);   // 8,388,608 f16
  _Float16* ccb  = (_Float16*)(ws + 12582912);  // 4,194,304 f16
  float* part1 = ws + 14680064;                 // 4,128,768 f32 (aliases vbuf slot)
  _Float16* vbuf = (_Float16*)part1;            // 8,388,608 f16
  float* part2 = ws + 2097152;                  // 4,194,304 f32 (aliases y1b slot; dead after attn1)
  _Float16* wpk  = (_Float16*)(ws + 19988480);  // 258,048 f16
  _Float16* wdyn = (_Float16*)(ws + 20117504);  // 589,824 f16
  float* accb  = ws + 20412416;                 // 8,388,608
  float* ysave = ws + 28801024;                 // 8,388,608
  float* xmean = ws + 37189632;
  float* xrstd = xmean + 64;
  float* vmean = xmean + 128;
  float* vrstd = xmean + 192;
  float* alphab = xmean + 256;
  float* betab  = xmean + 288;
  float* pstat  = xmean + 320;  // 1024

  bn_partial_kernel<float><<<dim3(64, 8), 256, 0, stream>>>(x, 64, pstat);
  bn_reduce_kernel<<<1, 64, 0, stream>>>(pstat, 32.f * HW, xmean, xrstd);
  pack_static_kernel<<<1008, 256, 0, stream>>>(wk1c1, wk1c2, wk2c1, wk2c2, wconv, wpk);

  for (int br = 0; br < 4; br++) {
    int ch0 = (br & 1) * 32;
    coeffs_kernel<<<1, 32, 0, stream>>>(xmean, xrstd, ch0, a_pre, br, alphab, betab);

    conv_mfma_kernel<0><<<dim3(16, 32), 256, 0, stream>>>(
        x, ch0, nullptr, wpk + (size_t)br * 64512, alphab, betab,
        y1a, y1b, y2a, y2b, ccb);

    // attn1 first (reads y1a/y1b), then attn2 (part2 overwrites the y1b slot)
    attn1_partial_kernel<<<dim3(21, 32, 2), 256, 0, stream>>>(y1a, y1b, part1);
    attn2_partial_kernel<<<dim3(64, 32), 256, 0, stream>>>(y2a, y2b, part2);
    fused_ak_kernel<<<dim3(64, 32), 320, 0, stream>>>(
        part1, part2, attn_w + (size_t)br * 64 * 288, wdyn);

    conv_mfma_kernel<1><<<dim3(16, 32), 256, 0, stream>>>(
        nullptr, 0, ccb, wdyn, nullptr, nullptr,
        vbuf, nullptr, nullptr, nullptr, nullptr);

    bn_partial_kernel<_Float16><<<dim3(64, 8), 256, 0, stream>>>(vbuf, 64, pstat);
    bn_reduce_kernel<<<1, 64, 0, stream>>>(pstat, 32.f * HW, vmean, vrstd);
    finalize_kernel<<<32768, 256, 0, stream>>>(
        vbuf, vmean, vrstd, a_post, br, br, accb, ysave, x, cm, out);
  }
}